// Round 1
// baseline (5949.501 us; speedup 1.0000x reference)
//
#include <hip/hip_runtime.h>
#include <math.h>

#define BATCH 8
#define CCH   256
#define HH    64
#define WW    64
#define NN    4096                    // HH*WW

#define BNC   (BATCH * NN * CCH)      // 8,388,608 floats per tensor
#define WT_PER_CONV (2304 * 256)      // 589,824 floats

// ---------------------------------------------------------------------------
// Weight transpose: Wt[conv][ci][tap][co] = w_conv[co][ci][tap]   (OIHW input)
// Makes conv-kernel weight staging fully coalesced (co fastest).
// ---------------------------------------------------------------------------
__global__ void wtrans_kernel(const float* __restrict__ w1,
                              const float* __restrict__ w2,
                              const float* __restrict__ w3,
                              float* __restrict__ Wt) {
    int e = blockIdx.x * 256 + threadIdx.x;      // 0 .. 3*589824-1
    int conv = e / WT_PER_CONV;
    int idx  = e % WT_PER_CONV;
    int co   = idx & 255;
    int tap  = (idx >> 8) % 9;
    int ci   = idx / (9 * 256);
    const float* src = (conv == 0) ? w1 : (conv == 1) ? w2 : w3;
    Wt[e] = src[co * 2304 + ci * 9 + tap];
}

// ---------------------------------------------------------------------------
// Conv 3x3 SAME + bias, output written TRANSPOSED: Out[b][n][co], n = h*64+w.
// Block: (conv, co-tile of 128, h row, batch). 256 threads = 32 tco x 8 tw.
// Per-thread tile: 4 co x 8 w.
// ---------------------------------------------------------------------------
__global__ __launch_bounds__(256)
void conv3x3_kernel(const float* __restrict__ X,
                    const float* __restrict__ Wt,
                    const float* __restrict__ b1,
                    const float* __restrict__ b2,
                    const float* __restrict__ b3,
                    float* __restrict__ out_qkv) {
    const int conv = blockIdx.x >> 1;
    const int co0  = (blockIdx.x & 1) * 128;
    const int h    = blockIdx.y;
    const int bb   = blockIdx.z;
    const int tid  = threadIdx.x;
    const int tco  = tid >> 3;    // 0..31
    const int tw   = tid & 7;     // 0..7

    __shared__ float Xs[8][3][68];    // [ci][row][1+w], col0 = w=-1, col65 = w=64
    __shared__ float Ws[8][9][128];   // [ci][tap][co]

    const float* bias = (conv == 0) ? b1 : (conv == 1) ? b2 : b3;
    float* Out = out_qkv + (size_t)conv * BNC + (size_t)bb * NN * CCH;
    const float* Wc = Wt + (size_t)conv * WT_PER_CONV;

    float acc[4][8];
#pragma unroll
    for (int i = 0; i < 4; ++i) {
        float bv = bias[co0 + tco * 4 + i];
#pragma unroll
        for (int j = 0; j < 8; ++j) acc[i][j] = bv;
    }

    // zero the halo columns once (never overwritten)
    if (tid < 48) {
        int ci = tid / 6, k = tid % 6;
        Xs[ci][k >> 1][(k & 1) ? 65 : 0] = 0.f;
    }

    for (int cc = 0; cc < 32; ++cc) {
        const int ci0 = cc * 8;
        __syncthreads();
        // stage X: 8 ci x 3 rows x 64 w = 1536 elems (coalesced)
#pragma unroll
        for (int t = 0; t < 6; ++t) {
            int idx = tid + t * 256;
            int w  = idx & 63;
            int r  = (idx >> 6) % 3;
            int ci = idx / 192;
            int hh = h - 1 + r;
            float v = 0.f;
            if (hh >= 0 && hh < HH)
                v = X[(((size_t)bb * CCH + ci0 + ci) * HH + hh) * WW + w];
            Xs[ci][r][w + 1] = v;
        }
        // stage W: 8 ci x 9 tap x 128 co = 9216 elems (coalesced)
#pragma unroll
        for (int t = 0; t < 36; ++t) {
            int idx = tid + t * 256;
            int co  = idx & 127;
            int tap = (idx >> 7) % 9;
            int ci  = idx / 1152;
            Ws[ci][tap][co] = Wc[((ci0 + ci) * 9 + tap) * 256 + co0 + co];
        }
        __syncthreads();

#pragma unroll
        for (int ci = 0; ci < 8; ++ci) {
#pragma unroll
            for (int kh = 0; kh < 3; ++kh) {
                float xr[10];
                const float4 x0 = *(const float4*)&Xs[ci][kh][tw * 8];
                const float4 x1 = *(const float4*)&Xs[ci][kh][tw * 8 + 4];
                const float2 x2 = *(const float2*)&Xs[ci][kh][tw * 8 + 8];
                xr[0] = x0.x; xr[1] = x0.y; xr[2] = x0.z; xr[3] = x0.w;
                xr[4] = x1.x; xr[5] = x1.y; xr[6] = x1.z; xr[7] = x1.w;
                xr[8] = x2.x; xr[9] = x2.y;
#pragma unroll
                for (int kw = 0; kw < 3; ++kw) {
                    const float4 wv = *(const float4*)&Ws[ci][kh * 3 + kw][tco * 4];
                    const float wa[4] = {wv.x, wv.y, wv.z, wv.w};
#pragma unroll
                    for (int i = 0; i < 4; ++i)
#pragma unroll
                        for (int j = 0; j < 8; ++j)
                            acc[i][j] += wa[i] * xr[j + kw];
                }
            }
        }
    }

    // write transposed: Out[n][co], float4 along co
#pragma unroll
    for (int j = 0; j < 8; ++j) {
        float4 v = make_float4(acc[0][j], acc[1][j], acc[2][j], acc[3][j]);
        *(float4*)&Out[(size_t)(h * WW + tw * 8 + j) * CCH + co0 + tco * 4] = v;
    }
}

// ---------------------------------------------------------------------------
// Flash attention, fp32 vector. Q=At, K=Bt, V=Dt, all [b][N][C].
// Block: 64 q-rows x one batch. 256 threads = 16 ti x 16 tj.
// S tile 64x64: thread rows i = ti*4+ii, cols j = tj+16*jj.
// O accumulator: rows i = ti*4+ii, cols c = vc*64 + tj*4 + cc.
// ---------------------------------------------------------------------------
__global__ __launch_bounds__(256)
void attn_kernel(const float* __restrict__ Qb,
                 const float* __restrict__ Kb,
                 const float* __restrict__ Vb,
                 const float* __restrict__ alpha_p,
                 float* __restrict__ out) {
    const int n0  = blockIdx.x * 64;
    const int bb  = blockIdx.y;
    const int tid = threadIdx.x;
    const int ti  = tid >> 4;    // 0..15
    const int tj  = tid & 15;    // 0..15

    __shared__ float Qs[64][36];
    __shared__ float Ks[64][36];
    __shared__ float PsT[64][68];   // [j][i]
    __shared__ float Vs[64][64];

    const float* Q = Qb + (size_t)bb * NN * CCH;
    const float* K = Kb + (size_t)bb * NN * CCH;
    const float* V = Vb + (size_t)bb * NN * CCH;

    float Oacc[4][4][4];   // [vc][cc][ii]
    float m_i[4], l_i[4];
#pragma unroll
    for (int vc = 0; vc < 4; ++vc)
#pragma unroll
        for (int cc = 0; cc < 4; ++cc)
#pragma unroll
            for (int ii = 0; ii < 4; ++ii) Oacc[vc][cc][ii] = 0.f;
#pragma unroll
    for (int ii = 0; ii < 4; ++ii) { m_i[ii] = -INFINITY; l_i[ii] = 0.f; }

    for (int mt = 0; mt < 64; ++mt) {
        const int m0 = mt * 64;
        float Sacc[4][4];
#pragma unroll
        for (int ii = 0; ii < 4; ++ii)
#pragma unroll
            for (int jj = 0; jj < 4; ++jj) Sacc[ii][jj] = 0.f;

        // ---- S = Q K^T over 256 channels, in 32-c chunks ----
        for (int cch = 0; cch < 8; ++cch) {
            __syncthreads();
#pragma unroll
            for (int t = 0; t < 8; ++t) {
                int idx = tid + t * 256;
                int c   = idx & 31;
                int row = idx >> 5;
                Qs[row][c] = Q[(size_t)(n0 + row) * CCH + cch * 32 + c];
                Ks[row][c] = K[(size_t)(m0 + row) * CCH + cch * 32 + c];
            }
            __syncthreads();
#pragma unroll
            for (int c4 = 0; c4 < 8; ++c4) {
                float4 qv[4], kv[4];
#pragma unroll
                for (int ii = 0; ii < 4; ++ii)
                    qv[ii] = *(const float4*)&Qs[ti * 4 + ii][c4 * 4];
#pragma unroll
                for (int jj = 0; jj < 4; ++jj)
                    kv[jj] = *(const float4*)&Ks[tj + 16 * jj][c4 * 4];
#pragma unroll
                for (int ii = 0; ii < 4; ++ii)
#pragma unroll
                    for (int jj = 0; jj < 4; ++jj)
                        Sacc[ii][jj] += qv[ii].x * kv[jj].x + qv[ii].y * kv[jj].y
                                      + qv[ii].z * kv[jj].z + qv[ii].w * kv[jj].w;
            }
        }

        // ---- online softmax (rows shared across the 16 tj lanes) ----
        float scale[4];
#pragma unroll
        for (int ii = 0; ii < 4; ++ii) {
            float mx = fmaxf(fmaxf(Sacc[ii][0], Sacc[ii][1]),
                             fmaxf(Sacc[ii][2], Sacc[ii][3]));
#pragma unroll
            for (int mask = 1; mask < 16; mask <<= 1)
                mx = fmaxf(mx, __shfl_xor(mx, mask, 64));
            float mnew = fmaxf(m_i[ii], mx);
            float rs = 0.f;
#pragma unroll
            for (int jj = 0; jj < 4; ++jj) {
                float p = __expf(Sacc[ii][jj] - mnew);
                Sacc[ii][jj] = p;
                rs += p;
            }
#pragma unroll
            for (int mask = 1; mask < 16; mask <<= 1)
                rs += __shfl_xor(rs, mask, 64);
            float sc = __expf(m_i[ii] - mnew);   // exp(-inf)=0 on first tile
            scale[ii] = sc;
            l_i[ii] = l_i[ii] * sc + rs;
            m_i[ii] = mnew;
        }
#pragma unroll
        for (int vc = 0; vc < 4; ++vc)
#pragma unroll
            for (int cc = 0; cc < 4; ++cc)
#pragma unroll
                for (int ii = 0; ii < 4; ++ii) Oacc[vc][cc][ii] *= scale[ii];

        // write P transposed to LDS (prev readers done: cchunk syncs intervened)
#pragma unroll
        for (int jj = 0; jj < 4; ++jj)
#pragma unroll
            for (int ii = 0; ii < 4; ++ii)
                PsT[tj + 16 * jj][ti * 4 + ii] = Sacc[ii][jj];

        // ---- O += P V in 64-c chunks ----
        for (int vc = 0; vc < 4; ++vc) {
            __syncthreads();
#pragma unroll
            for (int t = 0; t < 16; ++t) {
                int idx = tid + t * 256;
                int c   = idx & 63;
                int row = idx >> 6;
                Vs[row][c] = V[(size_t)(m0 + row) * CCH + vc * 64 + c];
            }
            __syncthreads();
#pragma unroll 8
            for (int j = 0; j < 64; ++j) {
                float4 p4 = *(const float4*)&PsT[j][ti * 4];
                float4 v4 = *(const float4*)&Vs[j][tj * 4];
                const float pa[4] = {p4.x, p4.y, p4.z, p4.w};
                const float va[4] = {v4.x, v4.y, v4.z, v4.w};
#pragma unroll
                for (int cc = 0; cc < 4; ++cc)
#pragma unroll
                    for (int ii = 0; ii < 4; ++ii)
                        Oacc[vc][cc][ii] += pa[ii] * va[cc];
            }
        }
    }

    // ---- epilogue: /l, *alpha, transposed write out[b][c][n] ----
    const float alpha = *alpha_p;
    float inv[4];
#pragma unroll
    for (int ii = 0; ii < 4; ++ii) inv[ii] = alpha / l_i[ii];

    float* Ob = out + (size_t)bb * CCH * NN;
#pragma unroll
    for (int vc = 0; vc < 4; ++vc)
#pragma unroll
        for (int cc = 0; cc < 4; ++cc) {
            int c = vc * 64 + tj * 4 + cc;
            float4 v = make_float4(Oacc[vc][cc][0] * inv[0],
                                   Oacc[vc][cc][1] * inv[1],
                                   Oacc[vc][cc][2] * inv[2],
                                   Oacc[vc][cc][3] * inv[3]);
            *(float4*)&Ob[(size_t)c * NN + n0 + ti * 4] = v;
        }
}

// ---------------------------------------------------------------------------
extern "C" void kernel_launch(void* const* d_in, const int* in_sizes, int n_in,
                              void* d_out, int out_size, void* d_ws, size_t ws_size,
                              hipStream_t stream) {
    const float* X  = (const float*)d_in[0];
    const float* w1 = (const float*)d_in[1];
    const float* b1 = (const float*)d_in[2];
    const float* w2 = (const float*)d_in[3];
    const float* b2 = (const float*)d_in[4];
    const float* w3 = (const float*)d_in[5];
    const float* b3 = (const float*)d_in[6];
    const float* alpha = (const float*)d_in[7];
    float* out = (float*)d_out;

    float* qkv = (float*)d_ws;                 // At,Bt,Dt: 3 * BNC floats
    float* Wt  = qkv + (size_t)3 * BNC;        // 3 * 589824 floats

    // 1) transpose weights (coalesced loads for conv)
    wtrans_kernel<<<dim3((3 * WT_PER_CONV) / 256), 256, 0, stream>>>(w1, w2, w3, Wt);

    // 2) three convs -> A^T, B^T, D^T in ws ([b][n][c])
    conv3x3_kernel<<<dim3(6, HH, BATCH), 256, 0, stream>>>(X, Wt, b1, b2, b3, qkv);

    // 3) flash attention + transposed scaled write-out
    attn_kernel<<<dim3(NN / 64, BATCH), 256, 0, stream>>>(
        qkv, qkv + (size_t)BNC, qkv + (size_t)2 * BNC, alpha, out);
}

// Round 2
// 2651.749 us; speedup vs baseline: 2.2436x; 2.2436x over previous
//
#include <hip/hip_runtime.h>
#include <math.h>

#define BATCH 8
#define CCH   256
#define HH    64
#define WW    64
#define NN    4096                    // HH*WW

#define BNC   (BATCH * NN * CCH)      // 8,388,608 elems per tensor
#define WT_PER_CONV (2304 * 256)      // 589,824 floats

typedef __bf16   bf16x8 __attribute__((ext_vector_type(8)));
typedef __bf16   bf16x4 __attribute__((ext_vector_type(4)));
typedef _Float16 f16x8  __attribute__((ext_vector_type(8)));
typedef float    f32x4  __attribute__((ext_vector_type(4)));

// ---------------------------------------------------------------------------
// Weight transpose: Wt[conv][ci][tap][co] = w_conv[co][ci][tap]   (OIHW input)
// ---------------------------------------------------------------------------
__global__ void wtrans_kernel(const float* __restrict__ w1,
                              const float* __restrict__ w2,
                              const float* __restrict__ w3,
                              float* __restrict__ Wt) {
    int e = blockIdx.x * 256 + threadIdx.x;
    int conv = e / WT_PER_CONV;
    int idx  = e % WT_PER_CONV;
    int co   = idx & 255;
    int tap  = (idx >> 8) % 9;
    int ci   = idx / (9 * 256);
    const float* src = (conv == 0) ? w1 : (conv == 1) ? w2 : w3;
    Wt[e] = src[co * 2304 + ci * 9 + tap];
}

// ---------------------------------------------------------------------------
// Conv 3x3 SAME + bias, output TRANSPOSED: Out[b][n][co], n = h*64+w. (fp32)
// ---------------------------------------------------------------------------
__global__ __launch_bounds__(256)
void conv3x3_kernel(const float* __restrict__ X,
                    const float* __restrict__ Wt,
                    const float* __restrict__ b1,
                    const float* __restrict__ b2,
                    const float* __restrict__ b3,
                    float* __restrict__ out_qkv) {
    const int conv = blockIdx.x >> 1;
    const int co0  = (blockIdx.x & 1) * 128;
    const int h    = blockIdx.y;
    const int bb   = blockIdx.z;
    const int tid  = threadIdx.x;
    const int tco  = tid >> 3;    // 0..31
    const int tw   = tid & 7;     // 0..7

    __shared__ float Xs[8][3][68];
    __shared__ float Ws[8][9][128];

    const float* bias = (conv == 0) ? b1 : (conv == 1) ? b2 : b3;
    float* Out = out_qkv + (size_t)conv * BNC + (size_t)bb * NN * CCH;
    const float* Wc = Wt + (size_t)conv * WT_PER_CONV;

    float acc[4][8];
#pragma unroll
    for (int i = 0; i < 4; ++i) {
        float bv = bias[co0 + tco * 4 + i];
#pragma unroll
        for (int j = 0; j < 8; ++j) acc[i][j] = bv;
    }

    if (tid < 48) {
        int ci = tid / 6, k = tid % 6;
        Xs[ci][k >> 1][(k & 1) ? 65 : 0] = 0.f;
    }

    for (int cc = 0; cc < 32; ++cc) {
        const int ci0 = cc * 8;
        __syncthreads();
#pragma unroll
        for (int t = 0; t < 6; ++t) {
            int idx = tid + t * 256;
            int w  = idx & 63;
            int r  = (idx >> 6) % 3;
            int ci = idx / 192;
            int hh = h - 1 + r;
            float v = 0.f;
            if (hh >= 0 && hh < HH)
                v = X[(((size_t)bb * CCH + ci0 + ci) * HH + hh) * WW + w];
            Xs[ci][r][w + 1] = v;
        }
#pragma unroll
        for (int t = 0; t < 36; ++t) {
            int idx = tid + t * 256;
            int co  = idx & 127;
            int tap = (idx >> 7) % 9;
            int ci  = idx / 1152;
            Ws[ci][tap][co] = Wc[((ci0 + ci) * 9 + tap) * 256 + co0 + co];
        }
        __syncthreads();

#pragma unroll
        for (int ci = 0; ci < 8; ++ci) {
#pragma unroll
            for (int kh = 0; kh < 3; ++kh) {
                float xr[10];
                const float4 x0 = *(const float4*)&Xs[ci][kh][tw * 8];
                const float4 x1 = *(const float4*)&Xs[ci][kh][tw * 8 + 4];
                const float2 x2 = *(const float2*)&Xs[ci][kh][tw * 8 + 8];
                xr[0] = x0.x; xr[1] = x0.y; xr[2] = x0.z; xr[3] = x0.w;
                xr[4] = x1.x; xr[5] = x1.y; xr[6] = x1.z; xr[7] = x1.w;
                xr[8] = x2.x; xr[9] = x2.y;
#pragma unroll
                for (int kw = 0; kw < 3; ++kw) {
                    const float4 wv = *(const float4*)&Ws[ci][kh * 3 + kw][tco * 4];
                    const float wa[4] = {wv.x, wv.y, wv.z, wv.w};
#pragma unroll
                    for (int i = 0; i < 4; ++i)
#pragma unroll
                        for (int j = 0; j < 8; ++j)
                            acc[i][j] += wa[i] * xr[j + kw];
                }
            }
        }
    }

#pragma unroll
    for (int j = 0; j < 8; ++j) {
        float4 v = make_float4(acc[0][j], acc[1][j], acc[2][j], acc[3][j]);
        *(float4*)&Out[(size_t)(h * WW + tw * 8 + j) * CCH + co0 + tco * 4] = v;
    }
}

// ---------------------------------------------------------------------------
// Split A,B (fp32 [b][n][c]) into bf16 hi/lo pairs (same layout).
// ---------------------------------------------------------------------------
__global__ __launch_bounds__(256)
void split_qk_kernel(const float* __restrict__ qkv,
                     __bf16* __restrict__ Qhi, __bf16* __restrict__ Qlo,
                     __bf16* __restrict__ Khi, __bf16* __restrict__ Klo) {
    const size_t i = ((size_t)blockIdx.x * 256 + threadIdx.x) * 4;
    const float4 v = *(const float4*)(qkv + i);
    const float a[4] = {v.x, v.y, v.z, v.w};
    bf16x4 h, l;
#pragma unroll
    for (int k = 0; k < 4; ++k) {
        const __bf16 hh = (__bf16)a[k];
        h[k] = hh;
        l[k] = (__bf16)(a[k] - (float)hh);   // residual exact in fp32
    }
    const bool isK = i >= (size_t)BNC;
    const size_t off = isK ? i - (size_t)BNC : i;
    *(bf16x4*)((isK ? Khi : Qhi) + off) = h;
    *(bf16x4*)((isK ? Klo : Qlo) + off) = l;
}

// ---------------------------------------------------------------------------
// Transpose D (fp32 [b][n][c]) -> Vt (fp16 [b][c][n]).
// ---------------------------------------------------------------------------
__global__ __launch_bounds__(256)
void transpose_v_kernel(const float* __restrict__ D, _Float16* __restrict__ Vt) {
    __shared__ float T[64][65];
    const int n0 = blockIdx.x * 64, c0 = blockIdx.y * 64, bb = blockIdx.z;
    const int t = threadIdx.x;
    const int row = t >> 2, q = (t & 3) * 16;
#pragma unroll
    for (int k = 0; k < 4; ++k) {
        float4 v = *(const float4*)(D + ((size_t)bb * NN + n0 + row) * CCH + c0 + q + k * 4);
        *(float4*)&T[row][q + k * 4] = v;
    }
    __syncthreads();
    f16x8 o0, o1;
#pragma unroll
    for (int j = 0; j < 8; ++j) o0[j] = (_Float16)T[q + j][row];
#pragma unroll
    for (int j = 0; j < 8; ++j) o1[j] = (_Float16)T[q + 8 + j][row];
    _Float16* dst = Vt + ((size_t)bb * CCH + c0 + row) * NN + n0 + q;
    *(f16x8*)dst = o0;
    *(f16x8*)(dst + 8) = o1;
}

// ---------------------------------------------------------------------------
// MFMA flash attention.
// Block: 512 threads = 8 waves; BM=128 (wave w owns q-rows n0+16w..+15).
// S = QK^T via split-bf16 3-pass mfma_f32_16x16x32_bf16 (K staged in LDS).
// PV via fp16 mfma (V fp16 [b][c][n], staged in LDS 64-c chunks).
// A-frag: lane holds T[m=lane&15][k=quad*8+j]; C/D: col=lane&15,row=quad*4+r.
// ---------------------------------------------------------------------------
__global__ __launch_bounds__(512, 2)
void attn_mfma_kernel(const __bf16* __restrict__ Qhi, const __bf16* __restrict__ Qlo,
                      const __bf16* __restrict__ Khi, const __bf16* __restrict__ Klo,
                      const _Float16* __restrict__ Vt, const float* __restrict__ alpha_p,
                      float* __restrict__ out) {
    const int bb = blockIdx.x & 7;     // batch -> XCD swizzle (L2 locality)
    const int qb = blockIdx.x >> 3;
    const int n0 = qb * 128;
    const int tid  = threadIdx.x;
    const int wave = tid >> 6;
    const int lane = tid & 63;
    const int quad = lane >> 4;
    const int l16  = lane & 15;

    __shared__ __bf16   KsHi[64][136];   // 64 kv rows x 128-c chunk (+8 pad)
    __shared__ __bf16   KsLo[64][136];
    __shared__ _Float16 Vs[64][72];      // 64-c chunk x 64 kv (+8 pad)
    __shared__ _Float16 Pb[8][16][72];   // per-wave P tile [i][j] (+8 pad)

    // Q fragments resident in registers for the whole kernel
    bf16x8 qhi[8], qlo[8];
    {
        const size_t base = ((size_t)bb * NN + n0 + wave * 16 + l16) * CCH + quad * 8;
#pragma unroll
        for (int ks = 0; ks < 8; ++ks) {
            qhi[ks] = *(const bf16x8*)(Qhi + base + ks * 32);
            qlo[ks] = *(const bf16x8*)(Qlo + base + ks * 32);
        }
    }

    f32x4 Oacc[16];
#pragma unroll
    for (int i = 0; i < 16; ++i) Oacc[i] = (f32x4){0.f, 0.f, 0.f, 0.f};
    float m_i[4], l_i[4];
#pragma unroll
    for (int r = 0; r < 4; ++r) { m_i[r] = -INFINITY; l_i[r] = 0.f; }

    const int krow = tid >> 3, kc = (tid & 7) * 16;   // K staging: 8 thr/row
    const int vrow = tid >> 3, vn = (tid & 7) * 8;    // V staging: 8 thr/row

    for (int mt = 0; mt < 64; ++mt) {
        const int m0 = mt * 64;
        f32x4 Sacc[4];
#pragma unroll
        for (int jt = 0; jt < 4; ++jt) Sacc[jt] = (f32x4){0.f, 0.f, 0.f, 0.f};

        // ---- S = Q K^T : two 128-channel chunks ----
        for (int cc = 0; cc < 2; ++cc) {
            __syncthreads();
            {
                const size_t g = ((size_t)bb * NN + m0 + krow) * CCH + cc * 128 + kc;
                *(bf16x8*)&KsHi[krow][kc]     = *(const bf16x8*)(Khi + g);
                *(bf16x8*)&KsHi[krow][kc + 8] = *(const bf16x8*)(Khi + g + 8);
                *(bf16x8*)&KsLo[krow][kc]     = *(const bf16x8*)(Klo + g);
                *(bf16x8*)&KsLo[krow][kc + 8] = *(const bf16x8*)(Klo + g + 8);
            }
            __syncthreads();
#pragma unroll
            for (int k2 = 0; k2 < 4; ++k2) {
                const int ks = cc * 4 + k2;
#pragma unroll
                for (int jt = 0; jt < 4; ++jt) {
                    bf16x8 kh = *(const bf16x8*)&KsHi[jt * 16 + l16][k2 * 32 + quad * 8];
                    bf16x8 kl = *(const bf16x8*)&KsLo[jt * 16 + l16][k2 * 32 + quad * 8];
                    Sacc[jt] = __builtin_amdgcn_mfma_f32_16x16x32_bf16(qhi[ks], kh, Sacc[jt], 0, 0, 0);
                    Sacc[jt] = __builtin_amdgcn_mfma_f32_16x16x32_bf16(qlo[ks], kh, Sacc[jt], 0, 0, 0);
                    Sacc[jt] = __builtin_amdgcn_mfma_f32_16x16x32_bf16(qhi[ks], kl, Sacc[jt], 0, 0, 0);
                }
            }
        }

        // ---- online softmax (row i = quad*4+r, cols across 16 low lanes) ----
        float p[4][4], scale[4];
#pragma unroll
        for (int r = 0; r < 4; ++r) {
            float mx = fmaxf(fmaxf(Sacc[0][r], Sacc[1][r]), fmaxf(Sacc[2][r], Sacc[3][r]));
#pragma unroll
            for (int mk = 1; mk < 16; mk <<= 1)
                mx = fmaxf(mx, __shfl_xor(mx, mk, 64));
            const float mnew = fmaxf(m_i[r], mx);
            float rs = 0.f;
#pragma unroll
            for (int jt = 0; jt < 4; ++jt) {
                const float pv = __expf(Sacc[jt][r] - mnew);
                p[jt][r] = pv; rs += pv;
            }
#pragma unroll
            for (int mk = 1; mk < 16; mk <<= 1)
                rs += __shfl_xor(rs, mk, 64);
            scale[r] = __expf(m_i[r] - mnew);   // exp(-inf)=0 on first tile
            l_i[r] = l_i[r] * scale[r] + rs;
            m_i[r] = mnew;
        }
#pragma unroll
        for (int ctg = 0; ctg < 16; ++ctg)
#pragma unroll
            for (int r = 0; r < 4; ++r) Oacc[ctg][r] *= scale[r];

        // P (C/D layout) -> per-wave LDS -> A-fragments (wave-local, no barrier)
#pragma unroll
        for (int jt = 0; jt < 4; ++jt)
#pragma unroll
            for (int r = 0; r < 4; ++r)
                Pb[wave][quad * 4 + r][jt * 16 + l16] = (_Float16)p[jt][r];
        f16x8 pf[2];
        pf[0] = *(const f16x8*)&Pb[wave][l16][quad * 8];
        pf[1] = *(const f16x8*)&Pb[wave][l16][32 + quad * 8];

        // ---- O += P V : four 64-channel chunks ----
        for (int cc4 = 0; cc4 < 4; ++cc4) {
            __syncthreads();
            {
                const size_t g = ((size_t)bb * CCH + cc4 * 64 + vrow) * NN + m0 + vn;
                *(f16x8*)&Vs[vrow][vn] = *(const f16x8*)(Vt + g);
            }
            __syncthreads();
#pragma unroll
            for (int ct = 0; ct < 4; ++ct) {
#pragma unroll
                for (int k2 = 0; k2 < 2; ++k2) {
                    f16x8 vf = *(const f16x8*)&Vs[ct * 16 + l16][k2 * 32 + quad * 8];
                    Oacc[cc4 * 4 + ct] =
                        __builtin_amdgcn_mfma_f32_16x16x32_f16(pf[k2], vf, Oacc[cc4 * 4 + ct], 0, 0, 0);
                }
            }
        }
    }

    // ---- epilogue: /l, *alpha, write out[b][c][n] (float4 along n) ----
    const float alpha = *alpha_p;
    float inv[4];
#pragma unroll
    for (int r = 0; r < 4; ++r) inv[r] = alpha / l_i[r];
    float* Ob = out + (size_t)bb * CCH * NN + n0 + wave * 16 + quad * 4;
#pragma unroll
    for (int ctg = 0; ctg < 16; ++ctg) {
        const int c = ctg * 16 + l16;
        float4 v;
        v.x = Oacc[ctg][0] * inv[0];
        v.y = Oacc[ctg][1] * inv[1];
        v.z = Oacc[ctg][2] * inv[2];
        v.w = Oacc[ctg][3] * inv[3];
        *(float4*)&Ob[(size_t)c * NN] = v;
    }
}

// ---------------------------------------------------------------------------
extern "C" void kernel_launch(void* const* d_in, const int* in_sizes, int n_in,
                              void* d_out, int out_size, void* d_ws, size_t ws_size,
                              hipStream_t stream) {
    const float* X  = (const float*)d_in[0];
    const float* w1 = (const float*)d_in[1];
    const float* b1 = (const float*)d_in[2];
    const float* w2 = (const float*)d_in[3];
    const float* b2 = (const float*)d_in[4];
    const float* w3 = (const float*)d_in[5];
    const float* b3 = (const float*)d_in[6];
    const float* alpha = (const float*)d_in[7];
    float* out = (float*)d_out;

    float*    qkv = (float*)d_ws;                       // 3*BNC fp32
    float*    Wt  = qkv + (size_t)3 * BNC;              // 3*WT_PER_CONV fp32
    __bf16*   Qhi = (__bf16*)(Wt + (size_t)3 * WT_PER_CONV);
    __bf16*   Qlo = Qhi + (size_t)BNC;
    __bf16*   Khi = Qlo + (size_t)BNC;
    __bf16*   Klo = Khi + (size_t)BNC;
    _Float16* Vt  = (_Float16*)(Klo + (size_t)BNC);

    wtrans_kernel<<<dim3((3 * WT_PER_CONV) / 256), 256, 0, stream>>>(w1, w2, w3, Wt);

    conv3x3_kernel<<<dim3(6, HH, BATCH), 256, 0, stream>>>(X, Wt, b1, b2, b3, qkv);

    split_qk_kernel<<<dim3((2 * BNC) / 1024), 256, 0, stream>>>(qkv, Qhi, Qlo, Khi, Klo);

    transpose_v_kernel<<<dim3(NN / 64, CCH / 64, BATCH), 256, 0, stream>>>(
        qkv + (size_t)2 * BNC, Vt);

    attn_mfma_kernel<<<dim3(256), 512, 0, stream>>>(Qhi, Qlo, Khi, Klo, Vt, alpha, out);
}

// Round 3
// 945.930 us; speedup vs baseline: 6.2896x; 2.8033x over previous
//
#include <hip/hip_runtime.h>
#include <math.h>

#define BATCH 8
#define CCH   256
#define HH    64
#define WW    64
#define NN    4096                    // HH*WW

#define BNC   (BATCH * NN * CCH)      // 8,388,608 elems per tensor
#define WELEMS (3 * 8 * 9 * 256 * 32) // 1,769,472 fp16 weight elems per hi/lo

typedef __bf16   bf16x8 __attribute__((ext_vector_type(8)));
typedef _Float16 f16x8  __attribute__((ext_vector_type(8)));
typedef float    f32x4  __attribute__((ext_vector_type(4)));

// ---------------------------------------------------------------------------
// Weights: OIHW fp32 -> fp16 hi/lo, layout [conv][cc8][tap9][co256][ci32]
// (flat-contiguous 16 KB blocks per (conv,cc,tap) => trivially coalesced
//  staging in the conv kernel).
// ---------------------------------------------------------------------------
__global__ void wtrans_kernel(const float* __restrict__ w1,
                              const float* __restrict__ w2,
                              const float* __restrict__ w3,
                              _Float16* __restrict__ Whi,
                              _Float16* __restrict__ Wlo) {
    int e = blockIdx.x * 256 + threadIdx.x;      // 0 .. WELEMS-1
    int t = e;
    const int ci  = t & 31;  t >>= 5;
    const int co  = t & 255; t >>= 8;
    const int tap = t % 9;   t /= 9;
    const int cc  = t & 7;   t >>= 3;
    const int conv = t;
    const float* src = (conv == 0) ? w1 : (conv == 1) ? w2 : w3;
    const float v = src[co * 2304 + (cc * 32 + ci) * 9 + tap];
    const _Float16 h = (_Float16)v;
    Whi[e] = h;
    Wlo[e] = (_Float16)(v - (float)h);
}

// ---------------------------------------------------------------------------
// X: [b][ci][h][w] fp32 -> Xhi/Xlo fp16 [b][h][w][ci]  (transpose via LDS)
// ---------------------------------------------------------------------------
__global__ __launch_bounds__(256)
void xsplit_kernel(const float* __restrict__ X,
                   _Float16* __restrict__ Xhi, _Float16* __restrict__ Xlo) {
    __shared__ float T[64][65];
    const int h = blockIdx.x, c0 = blockIdx.y * 64, bb = blockIdx.z;
    const int t = threadIdx.x;
    const int row = t >> 2, q = (t & 3) * 16;
#pragma unroll
    for (int k = 0; k < 4; ++k) {
        float4 v = *(const float4*)&X[(((size_t)bb * CCH + c0 + row) * HH + h) * WW + q + k * 4];
        *(float4*)&T[row][q + k * 4] = v;
    }
    __syncthreads();
    // row -> w, q -> ci offset
    f16x8 h0, h1, l0, l1;
#pragma unroll
    for (int j = 0; j < 8; ++j) {
        float v = T[q + j][row];
        _Float16 hh = (_Float16)v;
        h0[j] = hh; l0[j] = (_Float16)(v - (float)hh);
    }
#pragma unroll
    for (int j = 0; j < 8; ++j) {
        float v = T[q + 8 + j][row];
        _Float16 hh = (_Float16)v;
        h1[j] = hh; l1[j] = (_Float16)(v - (float)hh);
    }
    const size_t g = (((size_t)bb * HH + h) * WW + row) * CCH + c0 + q;
    *(f16x8*)(Xhi + g) = h0;  *(f16x8*)(Xhi + g + 8) = h1;
    *(f16x8*)(Xlo + g) = l0;  *(f16x8*)(Xlo + g + 8) = l1;
}

// ---------------------------------------------------------------------------
// MFMA implicit-GEMM conv 3x3 SAME + bias.
// Block: 512 thr (8 waves), tile BM=128 px (rows h0,h0+1) x BN=256 co.
// Waves: 2x4 grid -> each wave 4 M-tiles x 4 N-tiles (16 acc of f32x4).
// K-loop: 8 ci-chunks (32) x 9 taps. X staged per chunk (reused 9 taps),
// W staged per (chunk,tap) as one flat 16 KB block.
// conv 0/1 (A,B): 3-pass fp16 split -> write bf16 hi/lo [b][n][c].
// conv 2   (D):   1-pass fp16       -> write fp32 [b][n][c].
// ---------------------------------------------------------------------------
__global__ __launch_bounds__(512, 2)
void conv_mfma_kernel(const _Float16* __restrict__ Xhi, const _Float16* __restrict__ Xlo,
                      const _Float16* __restrict__ Whi, const _Float16* __restrict__ Wlo,
                      const float* __restrict__ b1, const float* __restrict__ b2,
                      const float* __restrict__ b3,
                      __bf16* __restrict__ Qhi, __bf16* __restrict__ Qlo,
                      __bf16* __restrict__ Khi, __bf16* __restrict__ Klo,
                      float* __restrict__ Dws) {
    const int h0   = blockIdx.x * 2;
    const int bb   = blockIdx.y;
    const int conv = blockIdx.z;
    const int tid  = threadIdx.x;
    const int wave = tid >> 6;
    const int lane = tid & 63;
    const int quad = lane >> 4;
    const int l16  = lane & 15;
    const int mg   = wave >> 2;       // 0,1 -> output row h0+mg
    const int ng   = wave & 3;        // co group of 64

    __shared__ _Float16 XsH[4 * 64 * 32];   // [row4][w64][ci32]
    __shared__ _Float16 XsL[4 * 64 * 32];
    __shared__ _Float16 WsH[256 * 32];      // [co][ci]
    __shared__ _Float16 WsL[256 * 32];

    const bool threePass = (conv < 2);
    const float* bias = (conv == 0) ? b1 : (conv == 1) ? b2 : b3;

    f32x4 acc[4][4];
#pragma unroll
    for (int j = 0; j < 4; ++j) {
        const float bv = bias[ng * 64 + j * 16 + l16];
#pragma unroll
        for (int i = 0; i < 4; ++i) acc[i][j] = (f32x4){bv, bv, bv, bv};
    }

    const f16x8 zf = {0, 0, 0, 0, 0, 0, 0, 0};

    // staging coords
    const int xrow = tid >> 7;            // 0..3
    const int xw   = (tid >> 1) & 63;
    const int xch  = (tid & 1) * 16;

    for (int cc = 0; cc < 8; ++cc) {
        for (int tap = 0; tap < 9; ++tap) {
            __syncthreads();
            if (tap == 0) {
                const int h = h0 - 1 + xrow;
                f16x8 a0 = zf, a1 = zf, b0 = zf, b1v = zf;
                if ((unsigned)h < (unsigned)HH) {
                    const size_t g = (((size_t)bb * HH + h) * WW + xw) * CCH + cc * 32 + xch;
                    a0 = *(const f16x8*)(Xhi + g);  a1 = *(const f16x8*)(Xhi + g + 8);
                    b0 = *(const f16x8*)(Xlo + g);  b1v = *(const f16x8*)(Xlo + g + 8);
                }
                const int l = (xrow * 64 + xw) * 32 + xch;
                *(f16x8*)&XsH[l] = a0;  *(f16x8*)&XsH[l + 8] = a1;
                *(f16x8*)&XsL[l] = b0;  *(f16x8*)&XsL[l + 8] = b1v;
            }
            {
                const size_t g = (((size_t)conv * 8 + cc) * 9 + tap) * 8192 + tid * 16;
                *(f16x8*)&WsH[tid * 16]     = *(const f16x8*)(Whi + g);
                *(f16x8*)&WsH[tid * 16 + 8] = *(const f16x8*)(Whi + g + 8);
                if (threePass) {
                    *(f16x8*)&WsL[tid * 16]     = *(const f16x8*)(Wlo + g);
                    *(f16x8*)&WsL[tid * 16 + 8] = *(const f16x8*)(Wlo + g + 8);
                }
            }
            __syncthreads();

            const int dh = tap / 3, dw = tap % 3;
            // A fragments (4 M-tiles)
            f16x8 ah[4], al[4];
#pragma unroll
            for (int i = 0; i < 4; ++i) {
                const int col = i * 16 + l16 + dw - 1;
                const bool ok = (unsigned)col < (unsigned)WW;
                const int colc = ok ? col : 0;
                const int off = ((mg + dh) * 64 + colc) * 32 + quad * 8;
                f16x8 th = *(const f16x8*)&XsH[off];
                ah[i] = ok ? th : zf;
                if (threePass) {
                    f16x8 tl = *(const f16x8*)&XsL[off];
                    al[i] = ok ? tl : zf;
                }
            }
#pragma unroll
            for (int j = 0; j < 4; ++j) {
                const int boff = (ng * 64 + j * 16 + l16) * 32 + quad * 8;
                const f16x8 bh = *(const f16x8*)&WsH[boff];
                if (threePass) {
                    const f16x8 bl = *(const f16x8*)&WsL[boff];
#pragma unroll
                    for (int i = 0; i < 4; ++i) {
                        acc[i][j] = __builtin_amdgcn_mfma_f32_16x16x32_f16(ah[i], bh, acc[i][j], 0, 0, 0);
                        acc[i][j] = __builtin_amdgcn_mfma_f32_16x16x32_f16(al[i], bh, acc[i][j], 0, 0, 0);
                        acc[i][j] = __builtin_amdgcn_mfma_f32_16x16x32_f16(ah[i], bl, acc[i][j], 0, 0, 0);
                    }
                } else {
#pragma unroll
                    for (int i = 0; i < 4; ++i)
                        acc[i][j] = __builtin_amdgcn_mfma_f32_16x16x32_f16(ah[i], bh, acc[i][j], 0, 0, 0);
                }
            }
        }
    }

    // ---- epilogue: [b][n][co]; A/B -> bf16 hi/lo, D -> fp32 ----
    const size_t nb = (size_t)bb * NN + (size_t)(h0 + mg) * 64;
    if (threePass) {
        __bf16* Hi = conv ? Khi : Qhi;
        __bf16* Lo = conv ? Klo : Qlo;
#pragma unroll
        for (int i = 0; i < 4; ++i) {
            const int wx0 = i * 16 + quad * 4;
#pragma unroll
            for (int j = 0; j < 4; ++j) {
                const int co = ng * 64 + j * 16 + l16;
#pragma unroll
                for (int r = 0; r < 4; ++r) {
                    const float v = acc[i][j][r];
                    const size_t idx = (nb + wx0 + r) * CCH + co;
                    const __bf16 h = (__bf16)v;
                    Hi[idx] = h;
                    Lo[idx] = (__bf16)(v - (float)h);
                }
            }
        }
    } else {
#pragma unroll
        for (int i = 0; i < 4; ++i) {
            const int wx0 = i * 16 + quad * 4;
#pragma unroll
            for (int j = 0; j < 4; ++j) {
                const int co = ng * 64 + j * 16 + l16;
#pragma unroll
                for (int r = 0; r < 4; ++r)
                    Dws[(nb + wx0 + r) * CCH + co] = acc[i][j][r];
            }
        }
    }
}

// ---------------------------------------------------------------------------
// Transpose D (fp32 [b][n][c]) -> Vt (fp16 [b][c][n]).
// ---------------------------------------------------------------------------
__global__ __launch_bounds__(256)
void transpose_v_kernel(const float* __restrict__ D, _Float16* __restrict__ Vt) {
    __shared__ float T[64][65];
    const int n0 = blockIdx.x * 64, c0 = blockIdx.y * 64, bb = blockIdx.z;
    const int t = threadIdx.x;
    const int row = t >> 2, q = (t & 3) * 16;
#pragma unroll
    for (int k = 0; k < 4; ++k) {
        float4 v = *(const float4*)(D + ((size_t)bb * NN + n0 + row) * CCH + c0 + q + k * 4);
        *(float4*)&T[row][q + k * 4] = v;
    }
    __syncthreads();
    f16x8 o0, o1;
#pragma unroll
    for (int j = 0; j < 8; ++j) o0[j] = (_Float16)T[q + j][row];
#pragma unroll
    for (int j = 0; j < 8; ++j) o1[j] = (_Float16)T[q + 8 + j][row];
    _Float16* dst = Vt + ((size_t)bb * CCH + c0 + row) * NN + n0 + q;
    *(f16x8*)dst = o0;
    *(f16x8*)(dst + 8) = o1;
}

// ---------------------------------------------------------------------------
// MFMA flash attention (unchanged from round 2).
// ---------------------------------------------------------------------------
__global__ __launch_bounds__(512, 2)
void attn_mfma_kernel(const __bf16* __restrict__ Qhi, const __bf16* __restrict__ Qlo,
                      const __bf16* __restrict__ Khi, const __bf16* __restrict__ Klo,
                      const _Float16* __restrict__ Vt, const float* __restrict__ alpha_p,
                      float* __restrict__ out) {
    const int bb = blockIdx.x & 7;
    const int qb = blockIdx.x >> 3;
    const int n0 = qb * 128;
    const int tid  = threadIdx.x;
    const int wave = tid >> 6;
    const int lane = tid & 63;
    const int quad = lane >> 4;
    const int l16  = lane & 15;

    __shared__ __bf16   KsHi[64][136];
    __shared__ __bf16   KsLo[64][136];
    __shared__ _Float16 Vs[64][72];
    __shared__ _Float16 Pb[8][16][72];

    bf16x8 qhi[8], qlo[8];
    {
        const size_t base = ((size_t)bb * NN + n0 + wave * 16 + l16) * CCH + quad * 8;
#pragma unroll
        for (int ks = 0; ks < 8; ++ks) {
            qhi[ks] = *(const bf16x8*)(Qhi + base + ks * 32);
            qlo[ks] = *(const bf16x8*)(Qlo + base + ks * 32);
        }
    }

    f32x4 Oacc[16];
#pragma unroll
    for (int i = 0; i < 16; ++i) Oacc[i] = (f32x4){0.f, 0.f, 0.f, 0.f};
    float m_i[4], l_i[4];
#pragma unroll
    for (int r = 0; r < 4; ++r) { m_i[r] = -INFINITY; l_i[r] = 0.f; }

    const int krow = tid >> 3, kc = (tid & 7) * 16;
    const int vrow = tid >> 3, vn = (tid & 7) * 8;

    for (int mt = 0; mt < 64; ++mt) {
        const int m0 = mt * 64;
        f32x4 Sacc[4];
#pragma unroll
        for (int jt = 0; jt < 4; ++jt) Sacc[jt] = (f32x4){0.f, 0.f, 0.f, 0.f};

        for (int cc = 0; cc < 2; ++cc) {
            __syncthreads();
            {
                const size_t g = ((size_t)bb * NN + m0 + krow) * CCH + cc * 128 + kc;
                *(bf16x8*)&KsHi[krow][kc]     = *(const bf16x8*)(Khi + g);
                *(bf16x8*)&KsHi[krow][kc + 8] = *(const bf16x8*)(Khi + g + 8);
                *(bf16x8*)&KsLo[krow][kc]     = *(const bf16x8*)(Klo + g);
                *(bf16x8*)&KsLo[krow][kc + 8] = *(const bf16x8*)(Klo + g + 8);
            }
            __syncthreads();
#pragma unroll
            for (int k2 = 0; k2 < 4; ++k2) {
                const int ks = cc * 4 + k2;
#pragma unroll
                for (int jt = 0; jt < 4; ++jt) {
                    bf16x8 kh = *(const bf16x8*)&KsHi[jt * 16 + l16][k2 * 32 + quad * 8];
                    bf16x8 kl = *(const bf16x8*)&KsLo[jt * 16 + l16][k2 * 32 + quad * 8];
                    Sacc[jt] = __builtin_amdgcn_mfma_f32_16x16x32_bf16(qhi[ks], kh, Sacc[jt], 0, 0, 0);
                    Sacc[jt] = __builtin_amdgcn_mfma_f32_16x16x32_bf16(qlo[ks], kh, Sacc[jt], 0, 0, 0);
                    Sacc[jt] = __builtin_amdgcn_mfma_f32_16x16x32_bf16(qhi[ks], kl, Sacc[jt], 0, 0, 0);
                }
            }
        }

        float p[4][4], scale[4];
#pragma unroll
        for (int r = 0; r < 4; ++r) {
            float mx = fmaxf(fmaxf(Sacc[0][r], Sacc[1][r]), fmaxf(Sacc[2][r], Sacc[3][r]));
#pragma unroll
            for (int mk = 1; mk < 16; mk <<= 1)
                mx = fmaxf(mx, __shfl_xor(mx, mk, 64));
            const float mnew = fmaxf(m_i[r], mx);
            float rs = 0.f;
#pragma unroll
            for (int jt = 0; jt < 4; ++jt) {
                const float pv = __expf(Sacc[jt][r] - mnew);
                p[jt][r] = pv; rs += pv;
            }
#pragma unroll
            for (int mk = 1; mk < 16; mk <<= 1)
                rs += __shfl_xor(rs, mk, 64);
            scale[r] = __expf(m_i[r] - mnew);
            l_i[r] = l_i[r] * scale[r] + rs;
            m_i[r] = mnew;
        }
#pragma unroll
        for (int ctg = 0; ctg < 16; ++ctg)
#pragma unroll
            for (int r = 0; r < 4; ++r) Oacc[ctg][r] *= scale[r];

#pragma unroll
        for (int jt = 0; jt < 4; ++jt)
#pragma unroll
            for (int r = 0; r < 4; ++r)
                Pb[wave][quad * 4 + r][jt * 16 + l16] = (_Float16)p[jt][r];
        f16x8 pf[2];
        pf[0] = *(const f16x8*)&Pb[wave][l16][quad * 8];
        pf[1] = *(const f16x8*)&Pb[wave][l16][32 + quad * 8];

        for (int cc4 = 0; cc4 < 4; ++cc4) {
            __syncthreads();
            {
                const size_t g = ((size_t)bb * CCH + cc4 * 64 + vrow) * NN + m0 + vn;
                *(f16x8*)&Vs[vrow][vn] = *(const f16x8*)(Vt + g);
            }
            __syncthreads();
#pragma unroll
            for (int ct = 0; ct < 4; ++ct) {
#pragma unroll
                for (int k2 = 0; k2 < 2; ++k2) {
                    f16x8 vf = *(const f16x8*)&Vs[ct * 16 + l16][k2 * 32 + quad * 8];
                    Oacc[cc4 * 4 + ct] =
                        __builtin_amdgcn_mfma_f32_16x16x32_f16(pf[k2], vf, Oacc[cc4 * 4 + ct], 0, 0, 0);
                }
            }
        }
    }

    const float alpha = *alpha_p;
    float inv[4];
#pragma unroll
    for (int r = 0; r < 4; ++r) inv[r] = alpha / l_i[r];
    float* Ob = out + (size_t)bb * CCH * NN + n0 + wave * 16 + quad * 4;
#pragma unroll
    for (int ctg = 0; ctg < 16; ++ctg) {
        const int c = ctg * 16 + l16;
        float4 v;
        v.x = Oacc[ctg][0] * inv[0];
        v.y = Oacc[ctg][1] * inv[1];
        v.z = Oacc[ctg][2] * inv[2];
        v.w = Oacc[ctg][3] * inv[3];
        *(float4*)&Ob[(size_t)c * NN] = v;
    }
}

// ---------------------------------------------------------------------------
extern "C" void kernel_launch(void* const* d_in, const int* in_sizes, int n_in,
                              void* d_out, int out_size, void* d_ws, size_t ws_size,
                              hipStream_t stream) {
    const float* X  = (const float*)d_in[0];
    const float* w1 = (const float*)d_in[1];
    const float* b1 = (const float*)d_in[2];
    const float* w2 = (const float*)d_in[3];
    const float* b2 = (const float*)d_in[4];
    const float* w3 = (const float*)d_in[5];
    const float* b3 = (const float*)d_in[6];
    const float* alpha = (const float*)d_in[7];
    float* out = (float*)d_out;

    // workspace layout (~158 MB)
    float*    Dws = (float*)d_ws;                         // BNC fp32
    __bf16*   Qhi = (__bf16*)(Dws + (size_t)BNC);
    __bf16*   Qlo = Qhi + (size_t)BNC;
    __bf16*   Khi = Qlo + (size_t)BNC;
    __bf16*   Klo = Khi + (size_t)BNC;
    _Float16* Vt  = (_Float16*)(Klo + (size_t)BNC);
    _Float16* Xhi = Vt + (size_t)BNC;
    _Float16* Xlo = Xhi + (size_t)BNC;
    _Float16* Whi = Xlo + (size_t)BNC;
    _Float16* Wlo = Whi + (size_t)WELEMS;

    wtrans_kernel<<<dim3(WELEMS / 256), 256, 0, stream>>>(w1, w2, w3, Whi, Wlo);

    xsplit_kernel<<<dim3(HH, CCH / 64, BATCH), 256, 0, stream>>>(X, Xhi, Xlo);

    conv_mfma_kernel<<<dim3(HH / 2, BATCH, 3), 512, 0, stream>>>(
        Xhi, Xlo, Whi, Wlo, b1, b2, b3, Qhi, Qlo, Khi, Klo, Dws);

    transpose_v_kernel<<<dim3(NN / 64, CCH / 64, BATCH), 256, 0, stream>>>(Dws, Vt);

    attn_mfma_kernel<<<dim3(256), 512, 0, stream>>>(Qhi, Qlo, Khi, Klo, Vt, alpha, out);
}